// Round 1
// baseline (116.329 us; speedup 1.0000x reference)
//
#include <hip/hip_runtime.h>
#include <stdint.h>

#define NR 16384
#define KI 256
#define MO 128
#define ALPHA 0.01f
#define CHUNK 128   // rows per suffix chunk; NR/CHUNK = 128 chunks

// ---------------- K1: h = x @ W^T  (fp32, 64x64 tile, 4x4 micro-tile) ----------------
__global__ __launch_bounds__(256) void k_gemm(const float* __restrict__ x,
                                              const float* __restrict__ w,
                                              float* __restrict__ h) {
    __shared__ float As[16][68];   // As[k][row]  (68 stride: 16B-aligned rows, 2-way max conflict)
    __shared__ float Bs[16][68];   // Bs[k][col]
    const int t = threadIdx.x;
    const int rowBase = blockIdx.x * 64;
    const int colBase = blockIdx.y * 64;
    const int tx = t & 15, ty = t >> 4;
    const int lr = t >> 2;         // 0..63 (row/col being staged)
    const int lk = (t & 3) << 2;   // 0,4,8,12 (k offset)
    float acc[4][4] = {};
    for (int k0 = 0; k0 < KI; k0 += 16) {
        float4 av = *(const float4*)&x[(rowBase + lr) * KI + k0 + lk];
        float4 bv = *(const float4*)&w[(colBase + lr) * KI + k0 + lk];
        __syncthreads();
        As[lk + 0][lr] = av.x; As[lk + 1][lr] = av.y;
        As[lk + 2][lr] = av.z; As[lk + 3][lr] = av.w;
        Bs[lk + 0][lr] = bv.x; Bs[lk + 1][lr] = bv.y;
        Bs[lk + 2][lr] = bv.z; Bs[lk + 3][lr] = bv.w;
        __syncthreads();
#pragma unroll
        for (int k = 0; k < 16; ++k) {
            float4 a4 = *(const float4*)&As[k][ty << 2];
            float4 b4 = *(const float4*)&Bs[k][tx << 2];
            float a[4] = {a4.x, a4.y, a4.z, a4.w};
            float b[4] = {b4.x, b4.y, b4.z, b4.w};
#pragma unroll
            for (int i = 0; i < 4; ++i)
#pragma unroll
                for (int j = 0; j < 4; ++j)
                    acc[i][j] = fmaf(a[i], b[j], acc[i][j]);
        }
    }
#pragma unroll
    for (int i = 0; i < 4; ++i) {
        float4 st = {acc[i][0], acc[i][1], acc[i][2], acc[i][3]};
        *(float4*)&h[(rowBase + (ty << 2) + i) * MO + colBase + (tx << 2)] = st;
    }
}

// ---------------- K2: s1 = h@a1, s2 = h@a2 (one wave per row-group) ----------------
__global__ __launch_bounds__(256) void k_s12(const float* __restrict__ h,
                                             const float* __restrict__ a1,
                                             const float* __restrict__ a2,
                                             float* __restrict__ s1,
                                             float* __restrict__ s2) {
    const int lane = threadIdx.x & 63;
    const int wave = threadIdx.x >> 6;
    const int wid = blockIdx.x * 4 + wave;   // 2048 waves, 8 rows each
    float2 w1 = *(const float2*)&a1[lane * 2];
    float2 w2 = *(const float2*)&a2[lane * 2];
    for (int r = 0; r < 8; ++r) {
        int row = wid * 8 + r;
        float2 hv = *(const float2*)&h[row * MO + lane * 2];
        float p1 = hv.x * w1.x + hv.y * w1.y;
        float p2 = hv.x * w2.x + hv.y * w2.y;
#pragma unroll
        for (int off = 32; off; off >>= 1) {
            p1 += __shfl_xor(p1, off, 64);
            p2 += __shfl_xor(p2, off, 64);
        }
        if (lane == 0) { s1[row] = p1; s2[row] = p2; }
    }
}

// sortable 46-bit key: float order primary, index tie-break (makes rank a bijection)
static __device__ __forceinline__ unsigned long long sort_key(float f, int j) {
    unsigned u = __float_as_uint(f);
    u ^= ((unsigned)((int)u >> 31)) | 0x80000000u;
    return (((unsigned long long)u) << 14) | (unsigned)(j & 0x3FFF);
}

// ---------------- K3: rank[i] = #{j : key_j < key_i}  (O(N^2) count, chunked) ----------------
__global__ __launch_bounds__(256) void k_rank(const float* __restrict__ s1,
                                              int* __restrict__ rank) {
    __shared__ unsigned long long sk[2048];
    const int t = threadIdx.x;
    const int i = blockIdx.x * 256 + t;
    const int jbase = blockIdx.y * 2048;
    for (int jj = t; jj < 2048; jj += 256)
        sk[jj] = sort_key(s1[jbase + jj], jbase + jj);
    __syncthreads();
    const unsigned long long ki = sort_key(s1[i], i);
    int cnt = 0;
#pragma unroll 8
    for (int jj = 0; jj < 2048; ++jj)
        cnt += (sk[jj] < ki) ? 1 : 0;
    atomicAdd(&rank[i], cnt);
}

// ---------------- K4: scatter into sorted order ----------------
__global__ __launch_bounds__(256) void k_scatter(const float* __restrict__ s1,
                                                 const int* __restrict__ rank,
                                                 float* __restrict__ s1s,
                                                 int* __restrict__ perm) {
    int i = blockIdx.x * 256 + threadIdx.x;
    int r = rank[i];
    s1s[r] = s1[i];
    perm[r] = i;
}

// ---------------- K5: kidx[i] = lower_bound(s1s, -s2[i]) ----------------
__global__ __launch_bounds__(256) void k_kidx(const float* __restrict__ s1s,
                                              const float* __restrict__ s2,
                                              int* __restrict__ kidx) {
    int i = blockIdx.x * 256 + threadIdx.x;
    float tv = -s2[i];
    int lo = 0, hi = NR;
    while (lo < hi) {
        int mid = (lo + hi) >> 1;
        if (s1s[mid] < tv) lo = mid + 1; else hi = mid;
    }
    kidx[i] = lo;
}

// ---------------- K6a: per-chunk partial sums of sorted h and s1*h ----------------
__global__ __launch_bounds__(128) void k_chunksum(const float* __restrict__ h,
                                                  const int* __restrict__ perm,
                                                  const float* __restrict__ s1s,
                                                  float* __restrict__ psumH,
                                                  float* __restrict__ psumSH) {
    __shared__ int pi[CHUNK];
    __shared__ float ss[CHUNK];
    const int c = threadIdx.x, q = blockIdx.x;
    pi[c] = perm[q * CHUNK + c];
    ss[c] = s1s[q * CHUNK + c];
    __syncthreads();
    float sh = 0.f, sshv = 0.f;
    for (int m = 0; m < CHUNK; ++m) {
        float v = h[pi[m] * MO + c];
        sh += v;
        sshv += ss[m] * v;
    }
    psumH[q * MO + c] = sh;
    psumSH[q * MO + c] = sshv;
}

// ---------------- K6c: full suffix-sum arrays SH[k], SSH[k], k in [0, NR] ----------------
__global__ __launch_bounds__(128) void k_suffix(const float* __restrict__ h,
                                                const int* __restrict__ perm,
                                                const float* __restrict__ s1s,
                                                const float* __restrict__ psumH,
                                                const float* __restrict__ psumSH,
                                                float* __restrict__ SH,
                                                float* __restrict__ SSH) {
    __shared__ int pi[CHUNK];
    __shared__ float ss[CHUNK];
    const int c = threadIdx.x, q = blockIdx.x;
    pi[c] = perm[q * CHUNK + c];
    ss[c] = s1s[q * CHUNK + c];
    __syncthreads();
    // exclusive suffix over later chunks (parallel per block; psum is L2-hot 64KB)
    float runH = 0.f, runS = 0.f;
    for (int q2 = q + 1; q2 < NR / CHUNK; ++q2) {
        runH += psumH[q2 * MO + c];
        runS += psumSH[q2 * MO + c];
    }
    for (int m = CHUNK - 1; m >= 0; --m) {
        int gm = q * CHUNK + m;
        float v = h[pi[m] * MO + c];
        runH += v;
        runS += ss[m] * v;
        SH[gm * MO + c] = runH;
        SSH[gm * MO + c] = runS;
    }
    if (q == 0) { SH[NR * MO + c] = 0.f; SSH[NR * MO + c] = 0.f; }
}

// ---------------- K7: out[i][c] = a*(s2*TH + TSH) + (1-a)*(s2*SH[k] + SSH[k]) ----------------
__global__ __launch_bounds__(256) void k_final(const float* __restrict__ SH,
                                               const float* __restrict__ SSH,
                                               const float* __restrict__ s2,
                                               const int* __restrict__ kidx,
                                               float* __restrict__ out) {
    int idx = blockIdx.x * 256 + threadIdx.x;
    int i = idx >> 7, c = idx & 127;
    float s2v = s2[i];
    int k = kidx[i];
    float th = SH[c], tsh = SSH[c];             // totals = suffix from 0
    float sh = SH[k * MO + c], sshv = SSH[k * MO + c];
    out[idx] = ALPHA * (s2v * th + tsh) + (1.f - ALPHA) * (s2v * sh + sshv);
}

extern "C" void kernel_launch(void* const* d_in, const int* in_sizes, int n_in,
                              void* d_out, int out_size, void* d_ws, size_t ws_size,
                              hipStream_t stream) {
    const float* x  = (const float*)d_in[0];   // [16384, 256]
    const float* w  = (const float*)d_in[1];   // [128, 256]
    const float* a1 = (const float*)d_in[2];   // [128]
    const float* a2 = (const float*)d_in[3];   // [128]
    float* out = (float*)d_out;                // [16384, 128]

    // workspace carve (~25.8 MB)
    float* ws     = (float*)d_ws;
    float* h      = ws;                              // NR*MO
    float* SH     = h + (size_t)NR * MO;             // (NR+1)*MO
    float* SSH    = SH + (size_t)(NR + 1) * MO;      // (NR+1)*MO
    float* s1     = SSH + (size_t)(NR + 1) * MO;     // NR
    float* s2     = s1 + NR;                         // NR
    float* s1s    = s2 + NR;                         // NR
    float* psumH  = s1s + NR;                        // 128*MO
    float* psumSH = psumH + (NR / CHUNK) * MO;       // 128*MO
    int*   rank   = (int*)(psumSH + (NR / CHUNK) * MO);
    int*   perm   = rank + NR;
    int*   kidx   = perm + NR;

    hipMemsetAsync(rank, 0, NR * sizeof(int), stream);

    k_gemm<<<dim3(NR / 64, MO / 64), 256, 0, stream>>>(x, w, h);
    k_s12<<<512, 256, 0, stream>>>(h, a1, a2, s1, s2);
    k_rank<<<dim3(NR / 256, 8), 256, 0, stream>>>(s1, rank);
    k_scatter<<<NR / 256, 256, 0, stream>>>(s1, rank, s1s, perm);
    k_kidx<<<NR / 256, 256, 0, stream>>>(s1s, s2, kidx);
    k_chunksum<<<NR / CHUNK, CHUNK, 0, stream>>>(h, perm, s1s, psumH, psumSH);
    k_suffix<<<NR / CHUNK, CHUNK, 0, stream>>>(h, perm, s1s, psumH, psumSH, SH, SSH);
    k_final<<<(NR * MO) / 256, 256, 0, stream>>>(SH, SSH, s2, kidx, out);
}